// Round 17
// baseline (46.375 us; speedup 1.0000x reference)
//
#include <hip/hip_runtime.h>
#include <hip/hip_bf16.h>
#include <math.h>

#define B 512
#define M 24
#define F 128
#define NRBF 20
#define CUTOFF 5.0f
#define SA_LD 40    // shorts/rbf row, fragment-packed: 4 slots x 8 shorts (80B)
#define SH_LD 140   // shorts/sH row (280B = 70dw)
#define CHUNK 8

// Single kernel, one block = one molecule, 8 waves, 2 blocks/CU (grid-exact).
//   P1 s@W1 -> h; P2 h@W2 -> phi chunks 0,2 (STAY IN REGISTERS);
//   P3 rbf_ext@Wf_ext per 8-i chunk, double-buffered produce/consume.
//   rbf_ext k: 0..19 = sin(nkd)/d (Chebyshev), 20 = mask, Wf row 20 = bf
//   -> C = (rbf@Wf+bf)*mask, exactly 0 for invalid pairs.
// A rows fragment-packed: consumer A-fragment = ONE ds_read_b128 (r14).
// r17: GEOMETRY MOVED OFF THE DS PIPE. The consume loop was DS-bound
// (11 DS/il x 24 il x 16 waves ~ 16us/CU serialized). Each lane's 8
// (rt,r) slots are 8 FIXED j's -> pos_j[8] lives in 24 VGPRs (one-time
// LDS load); pos_i is one broadcast b128 per il; rhat is computed inline
// (sub/fma/rsqrt/select ~ 14 VALU + 1 TRANS per j) with inv folded into
// m2 (rhat never materialized; invalid pair -> inv = 0). Deletes sGeoH,
// its producer writes, and 4 geo b128/il: DS/il 11 -> 8.
// Reduction: 4x shfl_xor(32) pair-sum + ONE shfl_xor(send,16) value-rotation;
// group g stores its own component (g0=ds, g1/2/3=dv_xyz).
// dv_v * v term of the reference is identically zero (v^0 = 0).
// Fragment layouts (v_mfma_f32_16x16x32_bf16):
//   C/D: col = lane&15, row = (lane>>4)*4 + reg            [m89-verified]
//   A/B: row/col = lane&15, k = (e>>2)*16 + 4*(lane>>4)+(e&3)

typedef __attribute__((ext_vector_type(8))) short short8;
typedef __attribute__((ext_vector_type(4))) float f32x4;

#define KIDX(g, e) ((((e) >> 2) << 4) + 4 * (g) + ((e) & 3))

__device__ __forceinline__ unsigned f2bf(float x) {
    unsigned u = __builtin_bit_cast(unsigned, x);
    return (u + 0x7FFFu + ((u >> 16) & 1u)) >> 16;   // RNE bf16
}

__device__ __forceinline__ short8 pack_frag(unsigned u0, unsigned u1,
                                            unsigned u2, unsigned u3) {
    uint4 t = make_uint4(u0, u1, u2, u3);
    return __builtin_bit_cast(short8, t);
}

// B-fragment from a global fp32 row-major matrix W[ld columns]
__device__ __forceinline__ short8 load_wfrag(const float* __restrict__ W, int ld,
                                             int col, int kbase, int g) {
    unsigned u[4];
#pragma unroll
    for (int q = 0; q < 4; ++q) {
        int k0 = kbase + KIDX(g, 2 * q);
        int k1 = kbase + KIDX(g, 2 * q + 1);
        u[q] = f2bf(W[(size_t)k0 * ld + col]) | (f2bf(W[(size_t)k1 * ld + col]) << 16);
    }
    return pack_frag(u[0], u[1], u[2], u[3]);
}

// B-fragment for the extended edge filter: rows 0..19 = Wf, row 20 = bf, rest 0
__device__ __forceinline__ short8 load_wffrag(const float* __restrict__ Wf,
                                              const float* __restrict__ bfv,
                                              int col, int g) {
    unsigned u[4];
#pragma unroll
    for (int q = 0; q < 4; ++q) {
        int k0 = KIDX(g, 2 * q);
        int k1 = KIDX(g, 2 * q + 1);
        float f0 = (k0 < NRBF) ? Wf[(size_t)k0 * (3 * F) + col] : (k0 == NRBF ? bfv[col] : 0.f);
        float f1 = (k1 < NRBF) ? Wf[(size_t)k1 * (3 * F) + col] : (k1 == NRBF ? bfv[col] : 0.f);
        u[q] = f2bf(f0) | (f2bf(f1) << 16);
    }
    return pack_frag(u[0], u[1], u[2], u[3]);
}

// A-fragment from LDS bf16 matrix with row stride `ldsh` shorts (k contiguous,
// KIDX gather) -- used for sH only
__device__ __forceinline__ short8 load_afrag(const short* sp, int row, int ldsh,
                                             int kbase, int g) {
    const short* p = sp + row * ldsh + kbase + 4 * g;
    uint2 lo = *(const uint2*)(p);
    uint2 hi = *(const uint2*)(p + 16);
    uint4 t = make_uint4(lo.x, lo.y, hi.x, hi.y);
    return __builtin_bit_cast(short8, t);
}

__global__ __launch_bounds__(512, 2) void painn_kernel(
    const int* __restrict__ atoms,
    const float* __restrict__ apos,
    const float* __restrict__ emb,
    const float* __restrict__ W1, const float* __restrict__ b1,
    const float* __restrict__ W2, const float* __restrict__ b2,
    const float* __restrict__ Wf, const float* __restrict__ bf,
    float* __restrict__ out)
{
    __shared__ __attribute__((aligned(16))) short sH[32 * SH_LD];
    __shared__ __attribute__((aligned(16))) short sA[2][CHUNK * 32 * SA_LD];
    __shared__ __attribute__((aligned(16))) float sPos[M][4];

    const int tid  = threadIdx.x;
    const int b    = blockIdx.x;
    const int wid  = tid >> 6;
    const int lane = tid & 63;
    const int g    = lane >> 4;
    const int lrow = lane & 15;
    const int f2   = wid * 16 + lrow;

    const float kth = 3.14159265358979323846f / CUTOFF;

    // ---- P0: s (emb gather) -> sH bf16, zero pad rows, positions --------
    for (int idx = tid; idx < M * 32; idx += 512) {
        int node = idx >> 5;
        int f4 = idx & 31;
        int a = atoms[b * M + node];
        float4 v = reinterpret_cast<const float4*>(emb + (size_t)a * F)[f4];
        unsigned u0 = f2bf(v.x) | (f2bf(v.y) << 16);
        unsigned u1 = f2bf(v.z) | (f2bf(v.w) << 16);
        *reinterpret_cast<uint2*>(&sH[node * SH_LD + f4 * 4]) = make_uint2(u0, u1);
    }
    for (int t = tid; t < 560; t += 512)               // rows 24..31 = 0
        reinterpret_cast<unsigned*>(sH)[1680 + t] = 0u;
    if (tid < M * 3) sPos[tid / 3][tid % 3] = apos[(size_t)b * M * 3 + tid];
    __syncthreads();

    // ---- P1: h = silu(s @ W1 + b1), MFMA --------------------------------
    {
        float b1v = b1[f2];
        f32x4 c[2] = {{0.f, 0.f, 0.f, 0.f}, {0.f, 0.f, 0.f, 0.f}};
#pragma unroll
        for (int ks = 0; ks < 4; ++ks) {
            short8 bfrag = load_wfrag(W1, F, f2, ks * 32, g);
            short8 a0 = load_afrag(sH, lrow, SH_LD, ks * 32, g);
            short8 a1 = load_afrag(sH, 16 + lrow, SH_LD, ks * 32, g);
            c[0] = __builtin_amdgcn_mfma_f32_16x16x32_bf16(a0, bfrag, c[0], 0, 0, 0);
            c[1] = __builtin_amdgcn_mfma_f32_16x16x32_bf16(a1, bfrag, c[1], 0, 0, 0);
        }
        __syncthreads();   // all s reads done before overwriting sH with h
#pragma unroll
        for (int rt = 0; rt < 2; ++rt)
#pragma unroll
            for (int r = 0; r < 4; ++r) {
                int row = rt * 16 + g * 4 + r;
                float x = c[rt][r] + b1v;
                float h = x / (1.0f + __expf(-x));
                sH[row * SH_LD + f2] = (short)f2bf(h);
            }
    }
    __syncthreads();

    // ---- P2: phi chunks 0,2 = h @ W2 + b2; KEPT IN REGISTERS ------------
    float ph0[8], ph2[8];
#pragma unroll
    for (int half = 0; half < 2; ++half) {
        int wcol = half ? (256 + f2) : f2;
        float b2v = b2[wcol];
        f32x4 c[2] = {{0.f, 0.f, 0.f, 0.f}, {0.f, 0.f, 0.f, 0.f}};
#pragma unroll
        for (int ks = 0; ks < 4; ++ks) {
            short8 bfrag = load_wfrag(W2, 3 * F, wcol, ks * 32, g);
            short8 a0 = load_afrag(sH, lrow, SH_LD, ks * 32, g);
            short8 a1 = load_afrag(sH, 16 + lrow, SH_LD, ks * 32, g);
            c[0] = __builtin_amdgcn_mfma_f32_16x16x32_bf16(a0, bfrag, c[0], 0, 0, 0);
            c[1] = __builtin_amdgcn_mfma_f32_16x16x32_bf16(a1, bfrag, c[1], 0, 0, 0);
        }
#pragma unroll
        for (int rt = 0; rt < 2; ++rt)
#pragma unroll
            for (int r = 0; r < 4; ++r) {
                if (half == 0) ph0[rt * 4 + r] = c[rt][r] + b2v;
                else           ph2[rt * 4 + r] = c[rt][r] + b2v;
            }
    }
    // no barrier needed: phi never touches LDS

    // ---- P3 setup: Wf fragments + register-resident pos_j ---------------
    short8 wfrag0 = load_wffrag(Wf, bf, f2, g);
    short8 wfrag2 = load_wffrag(Wf, bf, 256 + f2, g);

    // this lane's 8 fixed j's: j = rt*16 + g*4 + r  (q = rt*4 + r)
    float pjx[8], pjy[8], pjz[8];
    int   jidx[8];
#pragma unroll
    for (int rt = 0; rt < 2; ++rt)
#pragma unroll
        for (int r = 0; r < 4; ++r) {
            int q = rt * 4 + r;
            int j = rt * 16 + g * 4 + r;
            jidx[q] = j;
            if (j < M) {
                pjx[q] = sPos[j][0];
                pjy[q] = sPos[j][1];
                pjz[q] = sPos[j][2];
            } else {
                pjx[q] = 1e30f; pjy[q] = 1e30f; pjz[q] = 1e30f;
            }
        }

    const int pil = tid >> 5;          // producer row 0..7 (tid<256)
    const int pj  = tid & 31;          // producer col 0..31

    unsigned pk[16];

    auto produce = [&](int ic) {
#pragma unroll
        for (int q = 0; q < 16; ++q) pk[q] = 0u;
        int i = ic * CHUNK + pil;
        if (pj < M && pj != i) {
            float dx = sPos[i][0] - sPos[pj][0];
            float dy = sPos[i][1] - sPos[pj][1];
            float dz = sPos[i][2] - sPos[pj][2];
            float d = sqrtf(dx * dx + dy * dy + dz * dz);
            if (d < CUTOFF) {
                float inv = 1.0f / d;
                float s1, c1;
                __sincosf(kth * d, &s1, &c1);
                float cc = 2.0f * c1;
                float vp = s1 * inv;               // sin(1*th)/d
                float vc = 2.0f * s1 * c1 * inv;   // sin(2*th)/d
                pk[0] = f2bf(vp) | (f2bf(vc) << 16);
#pragma unroll
                for (int q = 1; q < 10; ++q) {
                    float v3 = cc * vc - vp;
                    float v4 = cc * v3 - vc;
                    pk[q] = f2bf(v3) | (f2bf(v4) << 16);
                    vp = v3; vc = v4;
                }
                pk[10] = 0x3F80u;                  // k=20: mask = bf16(1.0)
            }
        }
    };
    auto writebuf = [&](int buf) {
        // fragment-packed row: g-block gb = shorts {4gb..4gb+3, 16+4gb..16+4gb+3}
        short* rp = &sA[buf][(pil * 32 + pj) * SA_LD];
#pragma unroll
        for (int gb = 0; gb < 4; ++gb)
            *reinterpret_cast<uint4*>(rp + gb * 8) =
                make_uint4(pk[2 * gb], pk[2 * gb + 1], pk[8 + 2 * gb], pk[8 + 2 * gb + 1]);
    };

    if (tid < 256) { produce(0); writebuf(0); }
    __syncthreads();

    for (int ic = 0; ic < 3; ++ic) {
        const int buf = ic & 1;
        if (ic < 2 && tid < 256) { produce(ic + 1); writebuf(buf ^ 1); } // overlaps consume
#pragma unroll 2
        for (int il = 0; il < CHUNK; ++il) {
            const int i = ic * CHUNK + il;
            // pos_i: one broadcast b128 (wave-uniform address)
            float4 pi = *reinterpret_cast<const float4*>(&sPos[i][0]);
            float s0 = 0.f, ax = 0.f, ay = 0.f, az = 0.f;
#pragma unroll
            for (int rt = 0; rt < 2; ++rt) {
                // ONE b128: this (row, g)'s full A-fragment (packed layout)
                int row = il * 32 + rt * 16 + lrow;
                uint4 af = *reinterpret_cast<const uint4*>(&sA[buf][row * SA_LD + g * 8]);
                short8 afr = __builtin_bit_cast(short8, af);
                f32x4 z4 = {0.f, 0.f, 0.f, 0.f};
                f32x4 c0 = __builtin_amdgcn_mfma_f32_16x16x32_bf16(afr, wfrag0, z4, 0, 0, 0);
                f32x4 c2 = __builtin_amdgcn_mfma_f32_16x16x32_bf16(afr, wfrag2, z4, 0, 0, 0);
#pragma unroll
                for (int r = 0; r < 4; ++r) {
                    int q = rt * 4 + r;
                    float dx = pi.x - pjx[q];
                    float dy = pi.y - pjy[q];
                    float dz = pi.z - pjz[q];
                    float d2 = fmaf(dx, dx, fmaf(dy, dy, dz * dz));
                    bool valid = (d2 < CUTOFF * CUTOFF) && (jidx[q] != i);
                    float inv = valid ? rsqrtf(d2) : 0.f;
                    s0 = fmaf(c0[r], ph0[q], s0);
                    float m2 = c2[r] * ph2[q] * inv;   // inv folded: dv += m2 * (dx,dy,dz)
                    ax = fmaf(m2, dx, ax);
                    ay = fmaf(m2, dy, ay);
                    az = fmaf(m2, dz, az);
                }
            }
            // stage 1: pair-sum over lane^32 (g^2)
            s0 += __shfl_xor(s0, 32);
            ax += __shfl_xor(ax, 32);
            ay += __shfl_xor(ay, 32);
            az += __shfl_xor(az, 32);
            // stage 2: ONE shuffle over lane^16 (g^1), value-rotated
            float keep = (g == 0) ? s0 : (g == 1) ? ax : (g == 2) ? ay : az;
            float send = (g == 0) ? ax : (g == 1) ? s0 : (g == 2) ? az : ay;
            float v = keep + __shfl_xor(send, 16);
            const int node = b * M + i;
            float outv = v;
            int col;
            if (g == 0) {
                outv += emb[(size_t)atoms[node] * F + f2];
                col = f2;
            } else {
                col = F + 3 * f2 + (g - 1);
            }
            out[(size_t)node * (4 * F) + col] = outv;
        }
        __syncthreads();
    }
}

extern "C" void kernel_launch(void* const* d_in, const int* in_sizes, int n_in,
                              void* d_out, int out_size, void* d_ws, size_t ws_size,
                              hipStream_t stream) {
    const int*   atoms = (const int*)d_in[0];
    const float* apos  = (const float*)d_in[1];
    // d_in[2] = graph_indexes (unused; batch structure is the fixed [B,M] layout)
    const float* emb = (const float*)d_in[3];
    const float* W1  = (const float*)d_in[4];
    const float* b1  = (const float*)d_in[5];
    const float* W2  = (const float*)d_in[6];
    const float* b2  = (const float*)d_in[7];
    const float* Wf  = (const float*)d_in[8];
    const float* bf  = (const float*)d_in[9];
    float* out = (float*)d_out;

    painn_kernel<<<B, 512, 0, stream>>>(atoms, apos, emb, W1, b1, W2, b2, Wf, bf, out);
}

// Round 18
// 30.139 us; speedup vs baseline: 1.5387x; 1.5387x over previous
//
#include <hip/hip_runtime.h>
#include <hip/hip_bf16.h>
#include <hip/hip_fp16.h>
#include <math.h>

#define B 512
#define M 24
#define F 128
#define NRBF 20
#define CUTOFF 5.0f
#define SA_LD 40    // shorts/rbf row, fragment-packed: 4 slots x 8 shorts (80B)
#define SH_LD 140   // shorts/sH row (280B = 70dw)
#define CHUNK 8

// FINAL (r18 = exact r14 revert, measured best 30.2us).
// Single kernel, one block = one molecule, 8 waves, 2 blocks/CU (grid-exact).
//   P1 s@W1 -> h; P2 h@W2 -> phi chunks 0,2 (STAY IN REGISTERS);
//   P3 rbf_ext@Wf_ext per 8-i chunk, double-buffered produce/consume.
//   rbf_ext k: 0..19 = sin(nkd)/d (Chebyshev), 20 = mask, Wf row 20 = bf
//   -> C = (rbf@Wf+bf)*mask, exactly 0 for invalid pairs.
// A rows fragment-packed: g-block gb = shorts {4gb..4gb+3, 16+4gb..16+4gb+3};
// consumer A-fragment = ONE ds_read_b128 at row*40 + g*8 shorts.
// Geo as half4 in LDS, read as b128 pairs.
// Reduction: 4x shfl_xor(32) pair-sum + ONE shfl_xor(send,16) value-rotation;
// group g stores its own component (g0=ds, g1/2/3=dv_xyz).
// dv_v * v term of the reference is identically zero (v^0 = 0).
// Tried and rejected: permlane32_swap (r10/r11 corrupt: tied-operand
// coalescing), i-interleaved rows (r13: bank conflicts), slot-rotation
// swizzle (r15: conflicts unchanged -> sA not the source), full il unroll
// (r16: neutral -> not static-ILP-bound), VALU geometry (r17: VALU pipe
// saturated at 68%, +16us). Structural floor ~30us: ~11 DS-ops/il x 24 il
// x 16 waves/CU ~ 10-12us LDS-pipe + ~9us VALU + barrier/latency.
// Fragment layouts (v_mfma_f32_16x16x32_bf16):
//   C/D: col = lane&15, row = (lane>>4)*4 + reg            [m89-verified]
//   A/B: row/col = lane&15, k = (e>>2)*16 + 4*(lane>>4)+(e&3)

typedef __attribute__((ext_vector_type(8))) short short8;
typedef __attribute__((ext_vector_type(4))) float f32x4;

#define KIDX(g, e) ((((e) >> 2) << 4) + 4 * (g) + ((e) & 3))

__device__ __forceinline__ unsigned f2bf(float x) {
    unsigned u = __builtin_bit_cast(unsigned, x);
    return (u + 0x7FFFu + ((u >> 16) & 1u)) >> 16;   // RNE bf16
}
__device__ __forceinline__ unsigned f2h(float x) {
    return (unsigned)__builtin_bit_cast(unsigned short, __float2half(x));
}

__device__ __forceinline__ short8 pack_frag(unsigned u0, unsigned u1,
                                            unsigned u2, unsigned u3) {
    uint4 t = make_uint4(u0, u1, u2, u3);
    return __builtin_bit_cast(short8, t);
}

// B-fragment from a global fp32 row-major matrix W[ld columns]
__device__ __forceinline__ short8 load_wfrag(const float* __restrict__ W, int ld,
                                             int col, int kbase, int g) {
    unsigned u[4];
#pragma unroll
    for (int q = 0; q < 4; ++q) {
        int k0 = kbase + KIDX(g, 2 * q);
        int k1 = kbase + KIDX(g, 2 * q + 1);
        u[q] = f2bf(W[(size_t)k0 * ld + col]) | (f2bf(W[(size_t)k1 * ld + col]) << 16);
    }
    return pack_frag(u[0], u[1], u[2], u[3]);
}

// B-fragment for the extended edge filter: rows 0..19 = Wf, row 20 = bf, rest 0
__device__ __forceinline__ short8 load_wffrag(const float* __restrict__ Wf,
                                              const float* __restrict__ bfv,
                                              int col, int g) {
    unsigned u[4];
#pragma unroll
    for (int q = 0; q < 4; ++q) {
        int k0 = KIDX(g, 2 * q);
        int k1 = KIDX(g, 2 * q + 1);
        float f0 = (k0 < NRBF) ? Wf[(size_t)k0 * (3 * F) + col] : (k0 == NRBF ? bfv[col] : 0.f);
        float f1 = (k1 < NRBF) ? Wf[(size_t)k1 * (3 * F) + col] : (k1 == NRBF ? bfv[col] : 0.f);
        u[q] = f2bf(f0) | (f2bf(f1) << 16);
    }
    return pack_frag(u[0], u[1], u[2], u[3]);
}

// A-fragment from LDS bf16 matrix with row stride `ldsh` shorts (k contiguous,
// KIDX gather) -- used for sH only
__device__ __forceinline__ short8 load_afrag(const short* sp, int row, int ldsh,
                                             int kbase, int g) {
    const short* p = sp + row * ldsh + kbase + 4 * g;
    uint2 lo = *(const uint2*)(p);
    uint2 hi = *(const uint2*)(p + 16);
    uint4 t = make_uint4(lo.x, lo.y, hi.x, hi.y);
    return __builtin_bit_cast(short8, t);
}

__global__ __launch_bounds__(512, 2) void painn_kernel(
    const int* __restrict__ atoms,
    const float* __restrict__ apos,
    const float* __restrict__ emb,
    const float* __restrict__ W1, const float* __restrict__ b1,
    const float* __restrict__ W2, const float* __restrict__ b2,
    const float* __restrict__ Wf, const float* __restrict__ bf,
    float* __restrict__ out)
{
    __shared__ __attribute__((aligned(16))) short sH[32 * SH_LD];
    __shared__ __attribute__((aligned(16))) short sA[2][CHUNK * 32 * SA_LD];
    __shared__ __attribute__((aligned(16))) unsigned sGeoH[2][CHUNK * 32 * 2]; // half4 rhat
    __shared__ __attribute__((aligned(16))) float sPos[M][4];

    const int tid  = threadIdx.x;
    const int b    = blockIdx.x;
    const int wid  = tid >> 6;
    const int lane = tid & 63;
    const int g    = lane >> 4;
    const int lrow = lane & 15;
    const int f2   = wid * 16 + lrow;

    const float kth = 3.14159265358979323846f / CUTOFF;

    // ---- P0: s (emb gather) -> sH bf16, zero pad rows, positions --------
    for (int idx = tid; idx < M * 32; idx += 512) {
        int node = idx >> 5;
        int f4 = idx & 31;
        int a = atoms[b * M + node];
        float4 v = reinterpret_cast<const float4*>(emb + (size_t)a * F)[f4];
        unsigned u0 = f2bf(v.x) | (f2bf(v.y) << 16);
        unsigned u1 = f2bf(v.z) | (f2bf(v.w) << 16);
        *reinterpret_cast<uint2*>(&sH[node * SH_LD + f4 * 4]) = make_uint2(u0, u1);
    }
    for (int t = tid; t < 560; t += 512)               // rows 24..31 = 0
        reinterpret_cast<unsigned*>(sH)[1680 + t] = 0u;
    if (tid < M * 3) sPos[tid / 3][tid % 3] = apos[(size_t)b * M * 3 + tid];
    __syncthreads();

    // ---- P1: h = silu(s @ W1 + b1), MFMA --------------------------------
    {
        float b1v = b1[f2];
        f32x4 c[2] = {{0.f, 0.f, 0.f, 0.f}, {0.f, 0.f, 0.f, 0.f}};
#pragma unroll
        for (int ks = 0; ks < 4; ++ks) {
            short8 bfrag = load_wfrag(W1, F, f2, ks * 32, g);
            short8 a0 = load_afrag(sH, lrow, SH_LD, ks * 32, g);
            short8 a1 = load_afrag(sH, 16 + lrow, SH_LD, ks * 32, g);
            c[0] = __builtin_amdgcn_mfma_f32_16x16x32_bf16(a0, bfrag, c[0], 0, 0, 0);
            c[1] = __builtin_amdgcn_mfma_f32_16x16x32_bf16(a1, bfrag, c[1], 0, 0, 0);
        }
        __syncthreads();   // all s reads done before overwriting sH with h
#pragma unroll
        for (int rt = 0; rt < 2; ++rt)
#pragma unroll
            for (int r = 0; r < 4; ++r) {
                int row = rt * 16 + g * 4 + r;
                float x = c[rt][r] + b1v;
                float h = x / (1.0f + __expf(-x));
                sH[row * SH_LD + f2] = (short)f2bf(h);
            }
    }
    __syncthreads();

    // ---- P2: phi chunks 0,2 = h @ W2 + b2; KEPT IN REGISTERS ------------
    float ph0[8], ph2[8];
#pragma unroll
    for (int half = 0; half < 2; ++half) {
        int wcol = half ? (256 + f2) : f2;
        float b2v = b2[wcol];
        f32x4 c[2] = {{0.f, 0.f, 0.f, 0.f}, {0.f, 0.f, 0.f, 0.f}};
#pragma unroll
        for (int ks = 0; ks < 4; ++ks) {
            short8 bfrag = load_wfrag(W2, 3 * F, wcol, ks * 32, g);
            short8 a0 = load_afrag(sH, lrow, SH_LD, ks * 32, g);
            short8 a1 = load_afrag(sH, 16 + lrow, SH_LD, ks * 32, g);
            c[0] = __builtin_amdgcn_mfma_f32_16x16x32_bf16(a0, bfrag, c[0], 0, 0, 0);
            c[1] = __builtin_amdgcn_mfma_f32_16x16x32_bf16(a1, bfrag, c[1], 0, 0, 0);
        }
#pragma unroll
        for (int rt = 0; rt < 2; ++rt)
#pragma unroll
            for (int r = 0; r < 4; ++r) {
                if (half == 0) ph0[rt * 4 + r] = c[rt][r] + b2v;
                else           ph2[rt * 4 + r] = c[rt][r] + b2v;
            }
    }
    // no barrier needed: phi never touches LDS

    // ---- P3: Wf fragments + pipelined produce/consume -------------------
    short8 wfrag0 = load_wffrag(Wf, bf, f2, g);
    short8 wfrag2 = load_wffrag(Wf, bf, 256 + f2, g);

    const int pil = tid >> 5;          // producer row 0..7 (tid<256)
    const int pj  = tid & 31;          // producer col 0..31

    unsigned pk[16];
    unsigned gxy, gz;

    auto produce = [&](int ic) {
#pragma unroll
        for (int q = 0; q < 16; ++q) pk[q] = 0u;
        gxy = 0u; gz = 0u;
        int i = ic * CHUNK + pil;
        if (pj < M && pj != i) {
            float dx = sPos[i][0] - sPos[pj][0];
            float dy = sPos[i][1] - sPos[pj][1];
            float dz = sPos[i][2] - sPos[pj][2];
            float d = sqrtf(dx * dx + dy * dy + dz * dz);
            if (d < CUTOFF) {
                float inv = 1.0f / d;
                float s1, c1;
                __sincosf(kth * d, &s1, &c1);
                float cc = 2.0f * c1;
                float vp = s1 * inv;               // sin(1*th)/d
                float vc = 2.0f * s1 * c1 * inv;   // sin(2*th)/d
                pk[0] = f2bf(vp) | (f2bf(vc) << 16);
#pragma unroll
                for (int q = 1; q < 10; ++q) {
                    float v3 = cc * vc - vp;
                    float v4 = cc * v3 - vc;
                    pk[q] = f2bf(v3) | (f2bf(v4) << 16);
                    vp = v3; vc = v4;
                }
                pk[10] = 0x3F80u;                  // k=20: mask = bf16(1.0)
                gxy = f2h(dx * inv) | (f2h(dy * inv) << 16);
                gz  = f2h(dz * inv);
            }
        }
    };
    auto writebuf = [&](int buf) {
        // fragment-packed row: g-block gb = shorts {4gb..4gb+3, 16+4gb..16+4gb+3}
        short* rp = &sA[buf][(pil * 32 + pj) * SA_LD];
#pragma unroll
        for (int gb = 0; gb < 4; ++gb)
            *reinterpret_cast<uint4*>(rp + gb * 8) =
                make_uint4(pk[2 * gb], pk[2 * gb + 1], pk[8 + 2 * gb], pk[8 + 2 * gb + 1]);
        *reinterpret_cast<uint2*>(&sGeoH[buf][(pil * 32 + pj) * 2]) = make_uint2(gxy, gz);
    };

    if (tid < 256) { produce(0); writebuf(0); }
    __syncthreads();

    for (int ic = 0; ic < 3; ++ic) {
        const int buf = ic & 1;
        if (ic < 2 && tid < 256) { produce(ic + 1); writebuf(buf ^ 1); } // overlaps consume
#pragma unroll 2
        for (int il = 0; il < CHUNK; ++il) {
            const int i = ic * CHUNK + il;
            float s0 = 0.f, ax = 0.f, ay = 0.f, az = 0.f;
#pragma unroll
            for (int rt = 0; rt < 2; ++rt) {
                // ONE b128: this (row, g)'s full A-fragment (packed layout)
                int row = il * 32 + rt * 16 + lrow;
                uint4 af = *reinterpret_cast<const uint4*>(&sA[buf][row * SA_LD + g * 8]);
                short8 afr = __builtin_bit_cast(short8, af);
                f32x4 z4 = {0.f, 0.f, 0.f, 0.f};
                f32x4 c0 = __builtin_amdgcn_mfma_f32_16x16x32_bf16(afr, wfrag0, z4, 0, 0, 0);
                f32x4 c2 = __builtin_amdgcn_mfma_f32_16x16x32_bf16(afr, wfrag2, z4, 0, 0, 0);
                // geo for j = rt*16+g*4 + {0..3}: two b128 (2 half4 pairs each)
                const uint4* gp = reinterpret_cast<const uint4*>(
                    &sGeoH[buf][(il * 32 + rt * 16 + g * 4) * 2]);
                uint4 ga = gp[0], gb = gp[1];
#pragma unroll
                for (int r = 0; r < 4; ++r) {
                    unsigned pxy = (r == 0) ? ga.x : (r == 1) ? ga.z : (r == 2) ? gb.x : gb.z;
                    unsigned pzz = (r == 0) ? ga.y : (r == 1) ? ga.w : (r == 2) ? gb.y : gb.w;
                    __half2 hxy = __builtin_bit_cast(__half2, pxy);
                    float gx = __low2float(hxy);
                    float gy = __high2float(hxy);
                    float gzf = __low2float(__builtin_bit_cast(__half2, pzz));
                    s0 = fmaf(c0[r], ph0[rt * 4 + r], s0);
                    float m2 = c2[r] * ph2[rt * 4 + r];
                    ax = fmaf(m2, gx, ax);
                    ay = fmaf(m2, gy, ay);
                    az = fmaf(m2, gzf, az);
                }
            }
            // stage 1: pair-sum over lane^32 (g^2)
            s0 += __shfl_xor(s0, 32);
            ax += __shfl_xor(ax, 32);
            ay += __shfl_xor(ay, 32);
            az += __shfl_xor(az, 32);
            // stage 2: ONE shuffle over lane^16 (g^1), value-rotated
            float keep = (g == 0) ? s0 : (g == 1) ? ax : (g == 2) ? ay : az;
            float send = (g == 0) ? ax : (g == 1) ? s0 : (g == 2) ? az : ay;
            float v = keep + __shfl_xor(send, 16);
            const int node = b * M + i;
            float outv = v;
            int col;
            if (g == 0) {
                outv += emb[(size_t)atoms[node] * F + f2];
                col = f2;
            } else {
                col = F + 3 * f2 + (g - 1);
            }
            out[(size_t)node * (4 * F) + col] = outv;
        }
        __syncthreads();
    }
}

extern "C" void kernel_launch(void* const* d_in, const int* in_sizes, int n_in,
                              void* d_out, int out_size, void* d_ws, size_t ws_size,
                              hipStream_t stream) {
    const int*   atoms = (const int*)d_in[0];
    const float* apos  = (const float*)d_in[1];
    // d_in[2] = graph_indexes (unused; batch structure is the fixed [B,M] layout)
    const float* emb = (const float*)d_in[3];
    const float* W1  = (const float*)d_in[4];
    const float* b1  = (const float*)d_in[5];
    const float* W2  = (const float*)d_in[6];
    const float* b2  = (const float*)d_in[7];
    const float* Wf  = (const float*)d_in[8];
    const float* bf  = (const float*)d_in[9];
    float* out = (float*)d_out;

    painn_kernel<<<B, 512, 0, stream>>>(atoms, apos, emb, W1, b1, W2, b2, Wf, bf, out);
}